// Round 1
// baseline (130.605 us; speedup 1.0000x reference)
//
#include <hip/hip_runtime.h>

#define N_PTS  2048
#define BATCH  64
#define NSLICE 8
#define SLICE  (N_PTS / NSLICE)   // 256 search pts per block
#define P      8                  // query points per thread
#define BLK    256                // threads per block

static_assert(SLICE == BLK, "staging assumes one point per thread");
static_assert(P * BLK == N_PTS, "each block covers all queries of its (b,dir)");

// ---------------------------------------------------------------------------
// K1: partial chamfer mins.  grid (NSLICE, BATCH, 2 dirs), block 256.
//
// Old kernel was LDS-return-path bound: every thread re-read each search
// point (ds_read_b128 = 1 KiB/wave writeback even for broadcast) with only
// P=2 reuse -> pairs*10B = 5.4 GB LDS->VGPR = 78us @ 69 TB/s (measured 82us,
// 94% of that roofline; VALUBusy "82%" is the gfx94x 4-cyc formula, real
// ~41%).  P=8 cuts LDS bytes/pair 4x (下 to ~19us), exposing the 34us VALU
// floor (5 ops/pair).  Occupancy is restored by slicing the search side
// 8-ways (LDS 5KB/block, 1024 blocks, 4 blocks/CU = 4 waves/SIMD).
// Partial mins carry psq folded in (full |p-q|^2 >= 0), merged in K2.
// ---------------------------------------------------------------------------
template <bool ATOMIC>
__global__ __launch_bounds__(BLK, 4) void chamfer_partial(
        const float4* __restrict__ p,
        const float4* __restrict__ q,
        float* __restrict__ ws) {
    __shared__ float4 sQ[SLICE];        // 4 KB: search-side points
    __shared__ float4 sQs4[SLICE / 4];  // 1 KB: |q|^2 packed 4 per float4

    const int tid = threadIdx.x;
    const int s   = blockIdx.x;
    const int b   = blockIdx.y;
    const int dir = blockIdx.z;
    const float4* __restrict__ A  = dir ? q : p;   // query side
    const float4* __restrict__ Bm = dir ? p : q;   // search side
    const float4* __restrict__ Ab = A  + (size_t)b * N_PTS;
    const float4* __restrict__ Bb = Bm + (size_t)b * N_PTS + s * SLICE;

    {   // stage the slice: one point per thread, coalesced
        const float4 v = Bb[tid];
        sQ[tid] = v;
        ((float*)sQs4)[tid] = v.x * v.x + v.y * v.y + v.z * v.z + v.w * v.w;
    }
    __syncthreads();

    float4 pm[P];   // -2 * query point
    float  psq[P];
    float  mn[P];
#pragma unroll
    for (int k = 0; k < P; ++k) {
        const float4 pv = Ab[tid + k * BLK];
        psq[k] = pv.x * pv.x + pv.y * pv.y + pv.z * pv.z + pv.w * pv.w;
        pm[k]  = make_float4(-2.0f * pv.x, -2.0f * pv.y, -2.0f * pv.z, -2.0f * pv.w);
        mn[k]  = 3.4e38f;
    }

#define CHAMFER_STEP(JJ, QS)                          \
    {                                                 \
        const float4 qv = sQ[(JJ)];                   \
        _Pragma("unroll")                             \
        for (int k = 0; k < P; ++k) {                 \
            float t = fmaf(pm[k].x, qv.x, (QS));      \
            t = fmaf(pm[k].y, qv.y, t);               \
            t = fmaf(pm[k].z, qv.z, t);               \
            t = fmaf(pm[k].w, qv.w, t);               \
            mn[k] = fminf(mn[k], t);                  \
        }                                             \
    }

    for (int j = 0; j < SLICE; j += 4) {
        const float4 qs4 = sQs4[j >> 2];
        CHAMFER_STEP(j + 0, qs4.x)
        CHAMFER_STEP(j + 1, qs4.y)
        CHAMFER_STEP(j + 2, qs4.z)
        CHAMFER_STEP(j + 3, qs4.w)
    }
#undef CHAMFER_STEP

    const size_t qrow = (size_t)(dir * BATCH + b);
    if (ATOMIC) {
        // full squared distance >= 0 (up to ~1e-6 rounding), so IEEE bits
        // compare correctly as ints; atomicMin is exact & deterministic.
        int* wi = (int*)ws + qrow * N_PTS;
#pragma unroll
        for (int k = 0; k < P; ++k)
            atomicMin(wi + tid + k * BLK, __float_as_int(mn[k] + psq[k]));
    } else {
        float* wf = ws + (qrow * NSLICE + s) * N_PTS;
#pragma unroll
        for (int k = 0; k < P; ++k)
            wf[tid + k * BLK] = mn[k] + psq[k];
    }
}

// ---------------------------------------------------------------------------
// K2: merge slice partials, sum chamfer, add jet term.  grid (BATCH), 256 thr.
// ---------------------------------------------------------------------------
template <bool ATOMIC>
__global__ __launch_bounds__(BLK) void chamfer_reduce(
        const float4* __restrict__ p,
        const float4* __restrict__ q,
        const float* __restrict__ ws,
        float* __restrict__ out) {
    __shared__ float r0[4], r1[4], r2[4], r3[4], r4[4];
    const int tid = threadIdx.x;
    const int b   = blockIdx.x;

    float acc = 0.0f;
#pragma unroll
    for (int dir = 0; dir < 2; ++dir) {
        if (ATOMIC) {
            const int* wi = (const int*)ws + (size_t)(dir * BATCH + b) * N_PTS;
            for (int i = tid; i < N_PTS; i += BLK)
                acc += __int_as_float(wi[i]);
        } else {
            const float* wf = ws + (size_t)(dir * BATCH + b) * NSLICE * N_PTS;
            for (int i = tid; i < N_PTS; i += BLK) {
                float m = wf[i];
#pragma unroll
                for (int s2 = 1; s2 < NSLICE; ++s2)
                    m = fminf(m, wf[s2 * N_PTS + i]);
                acc += m;
            }
        }
    }

    // jet term: per-batch sum of (p - q), then |.|^2
    float ax = 0.f, ay = 0.f, az = 0.f, aw = 0.f;
    const float4* __restrict__ Pb = p + (size_t)b * N_PTS;
    const float4* __restrict__ Qb = q + (size_t)b * N_PTS;
    for (int i = tid; i < N_PTS; i += BLK) {
        const float4 pv = Pb[i];
        const float4 qv = Qb[i];
        ax += pv.x - qv.x;
        ay += pv.y - qv.y;
        az += pv.z - qv.z;
        aw += pv.w - qv.w;
    }

#pragma unroll
    for (int off = 32; off > 0; off >>= 1) {
        acc += __shfl_down(acc, off, 64);
        ax  += __shfl_down(ax,  off, 64);
        ay  += __shfl_down(ay,  off, 64);
        az  += __shfl_down(az,  off, 64);
        aw  += __shfl_down(aw,  off, 64);
    }
    const int lane = tid & 63;
    const int wid  = tid >> 6;
    if (lane == 0) { r0[wid] = acc; r1[wid] = ax; r2[wid] = ay; r3[wid] = az; r4[wid] = aw; }
    __syncthreads();
    if (tid == 0) {
        float sc = 0.f, dx = 0.f, dy = 0.f, dz = 0.f, dw = 0.f;
#pragma unroll
        for (int w = 0; w < 4; ++w) {
            sc += r0[w]; dx += r1[w]; dy += r2[w]; dz += r3[w]; dw += r4[w];
        }
        atomicAdd(out, sc + dx * dx + dy * dy + dz * dz + dw * dw);
    }
}

extern "C" void kernel_launch(void* const* d_in, const int* in_sizes, int n_in,
                              void* d_out, int out_size, void* d_ws, size_t ws_size,
                              hipStream_t stream) {
    const float4* p = (const float4*)d_in[0];
    const float4* q = (const float4*)d_in[1];
    float* out = (float*)d_out;
    float* ws  = (float*)d_ws;

    hipMemsetAsync(out, 0, sizeof(float), stream);

    const size_t need_plain = (size_t)2 * BATCH * NSLICE * N_PTS * sizeof(float); // 8 MB
    if (ws_size >= need_plain) {
        // deterministic plain-store path, no atomics in the hot kernel
        chamfer_partial<false><<<dim3(NSLICE, BATCH, 2), BLK, 0, stream>>>(p, q, ws);
        chamfer_reduce<false><<<BATCH, BLK, 0, stream>>>(p, q, ws, out);
    } else {
        // compact 1 MB path: init to large positive float (0x7F7F7F7F), atomicMin merge
        hipMemsetAsync(ws, 0x7F, (size_t)2 * BATCH * N_PTS * sizeof(float), stream);
        chamfer_partial<true><<<dim3(NSLICE, BATCH, 2), BLK, 0, stream>>>(p, q, ws);
        chamfer_reduce<true><<<BATCH, BLK, 0, stream>>>(p, q, ws, out);
    }
}